// Round 6
// baseline (6720.339 us; speedup 1.0000x reference)
//
#include <hip/hip_runtime.h>
#include <hip/hip_bf16.h>

#define SEQ   2048
#define NBATCH 64
#define HID   512
#define KDIM  512

typedef float f32x4  __attribute__((ext_vector_type(4)));
typedef short bf16x8 __attribute__((ext_vector_type(8)));

__device__ __forceinline__ unsigned short f2bf(float f) {
  union { float f; unsigned int u; } v; v.f = f;
  unsigned int r = v.u + 0x7FFFu + ((v.u >> 16) & 1u);
  return (unsigned short)(r >> 16);
}

__device__ __forceinline__ f32x4 mfma16(bf16x8 a, bf16x8 b, f32x4 c) {
  return __builtin_amdgcn_mfma_f32_16x16x32_bf16(a, b, c, 0, 0, 0);
}

// Repack W [H=512 rows n][K=512 cols k] (row-major fp32) into MFMA-fragment-major bf16:
// element index = ((kf*32 + cfg)*64 + lane)*8 + e  with n = cfg*16 + (lane&15),
// k = kf*32 + (lane>>4)*8 + e.  Used as B-frag (phase 1) and A-frag (scan).
__global__ void prep_wfrag(const float* __restrict__ W, unsigned short* __restrict__ dst) {
  int tid = blockIdx.x * blockDim.x + threadIdx.x;   // 0 .. 262143
  int e   = tid & 7;
  int l   = (tid >> 3) & 63;
  int cfg = (tid >> 9) & 31;
  int kf  = tid >> 14;
  int n = cfg * 16 + (l & 15);
  int k = kf * 32 + (l >> 4) * 8 + e;
  dst[tid] = f2bf(W[n * KDIM + k]);
}

__global__ void prep_bsum(const float* __restrict__ a, const float* __restrict__ b,
                          float* __restrict__ out) {
  int j = threadIdx.x;
  if (j < HID) out[j] = a[j] + b[j];
}

// Phase 1: xp = X * W_ih^T + (b_ih + b_hh), NATURAL layout [s*64+b][n] fp32.
__global__ __launch_bounds__(512) void rnn_xproj(
    const float* __restrict__ X,      // [131072, 512] fp32
    const uint4* __restrict__ BW,     // W_ih frag-major bf16
    const float* __restrict__ bsum,   // [512]
    float* __restrict__ out) {        // [131072, 512] fp32 (xp)
  const int tid = threadIdx.x, w = tid >> 6, l = tid & 63;
  const int g = l >> 4, lr = l & 15;
  const int rowbase = blockIdx.x * 64 + (w >> 2) * 32;
  const int colw = (w & 3) * 128;

  f32x4 acc[2][8];
  #pragma unroll
  for (int cf = 0; cf < 8; ++cf) {
    float bv = bsum[colw + cf * 16 + lr];
    f32x4 z = {bv, bv, bv, bv};
    acc[0][cf] = z; acc[1][cf] = z;
  }

  #pragma unroll 1
  for (int kc = 0; kc < 16; ++kc) {
    const int kb = kc * 32 + g * 8;
    bf16x8 afr[2];
    #pragma unroll
    for (int ai = 0; ai < 2; ++ai) {
      const float* src = X + (size_t)(rowbase + ai * 16 + lr) * KDIM + kb;
      float4 lo = *reinterpret_cast<const float4*>(src);
      float4 hi = *reinterpret_cast<const float4*>(src + 4);
      bf16x8 a;
      a[0] = (short)f2bf(lo.x); a[1] = (short)f2bf(lo.y);
      a[2] = (short)f2bf(lo.z); a[3] = (short)f2bf(lo.w);
      a[4] = (short)f2bf(hi.x); a[5] = (short)f2bf(hi.y);
      a[6] = (short)f2bf(hi.z); a[7] = (short)f2bf(hi.w);
      afr[ai] = a;
    }
    #pragma unroll
    for (int cf = 0; cf < 8; ++cf) {
      const int cfg = (w & 3) * 8 + cf;
      uint4 braw = BW[(kc * 32 + cfg) * 64 + l];
      bf16x8 b = __builtin_bit_cast(bf16x8, braw);
      acc[0][cf] = mfma16(afr[0], b, acc[0][cf]);
      acc[1][cf] = mfma16(afr[1], b, acc[1][cf]);
    }
  }

  #pragma unroll
  for (int ai = 0; ai < 2; ++ai) {
    #pragma unroll
    for (int cf = 0; cf < 8; ++cf) {
      const int col = colw + cf * 16 + lr;
      #pragma unroll
      for (int r = 0; r < 4; ++r) {
        const int row = rowbase + ai * 16 + g * 4 + r;
        out[(size_t)row * HID + col] = acc[ai][cf][r];
      }
    }
  }
}

// Phase 2: sequential scan, orientation-swapped: D[n_out][b] = sum_k W[n_out][k] h[b][k].
// 4 blocks x 512 threads (8 waves, 2/SIMD). Wave w owns mf = w*4..w*4+3.
// LDS (163840 B): [0,131072) W_hh kf0-3 A-frags (linear); [131072,+16K) h buf0;
// [147456,+16K) h buf1 (rows XOR-swizzled by ((b&7)<<4)). W_hh kf4..15 in 192 regs.
// Step pipeline: kf order 4,0,5,1,6,2,7,3,8..15 with depth-1 named prefetch of hb/A.
__global__ __launch_bounds__(512, 2) void rnn_scan(
    const uint4* __restrict__ BW,   // W_hh frag-major bf16 (16384 frags)
    float* __restrict__ xo) {       // d_out: xp in (natural), h out (natural)
  extern __shared__ char smem[];
  const int tid = threadIdx.x, w = tid >> 6, l = tid & 63;
  const int g = l >> 4, lr = l & 15;
  const int bg = blockIdx.x;

  // stage W_hh kf0-3 (128 KB, linear)
  {
    uint4* lb = reinterpret_cast<uint4*>(smem);
    #pragma unroll
    for (int i = 0; i < 16; ++i) lb[i * 512 + tid] = BW[i * 512 + tid];
  }
  // zero h buf0
  {
    float* hz = reinterpret_cast<float*>(smem + 131072);
    #pragma unroll
    for (int i = 0; i < 8; ++i) hz[i * 512 + tid] = 0.f;
  }
  // register A-frags kf4..15 for this wave's 4 m-frags (static indices only)
  bf16x8 ar[12][4];
  #pragma unroll
  for (int kf = 0; kf < 12; ++kf)
    #pragma unroll
    for (int mf = 0; mf < 4; ++mf)
      ar[kf][mf] = __builtin_bit_cast(bf16x8,
          BW[((kf + 4) * 32 + (w * 4 + mf)) * 64 + l]);
  __syncthreads();

  // per-lane constants
  const int hswz = (lr & 7) << 4;
  const int bpre = lr * 1024 + g * 16;                 // + kf*64, ^hswz, + hbase
  const int apre = (w * 4) * 1024 + l * 16;            // + kf*32768 + mf*1024
  const int wpre = lr * 1024 + (w * 4) * 32 + g * 8;   // + mf*32, ^hswz, + hbase
  float* xrow0 = xo + ((size_t)bg * 16 + lr) * HID + (size_t)(w * 4) * 16 + g * 4;

#define HB(kf, RD) (*reinterpret_cast<const bf16x8*>(                            \
    smem + 131072 + (RD) + ((bpre + (kf) * 64) ^ hswz)))
#define AF(kf, mf) (*reinterpret_cast<const bf16x8*>(                            \
    smem + ((kf) * 32768) + apre + (mf) * 1024))
#define M4R(i, hb)                                                               \
  acc0 = mfma16(ar[i][0], hb, acc0); acc1 = mfma16(ar[i][1], hb, acc1);          \
  acc2 = mfma16(ar[i][2], hb, acc2); acc3 = mfma16(ar[i][3], hb, acc3);
#define M4L(hb)                                                                  \
  acc0 = mfma16(a0, hb, acc0); acc1 = mfma16(a1, hb, acc1);                      \
  acc2 = mfma16(a2, hb, acc2); acc3 = mfma16(a3, hb, acc3);

#define SCAN_STEP(S, RD, WR)                                                     \
  {                                                                              \
    const int s = (S);                                                           \
    f32x4 acc0 = {0,0,0,0}, acc1 = {0,0,0,0}, acc2 = {0,0,0,0}, acc3 = {0,0,0,0};\
    bf16x8 hb_c, hb_n, a0, a1, a2, a3;                                           \
    hb_c = HB(4, RD);                                                            \
    /* p0: kf4 (reg A)  — prefetch kf0 operands */                               \
    hb_n = HB(0, RD);                                                            \
    a0 = AF(0, 0); a1 = AF(0, 1); a2 = AF(0, 2); a3 = AF(0, 3);                  \
    M4R(0, hb_c)                                                                 \
    /* p1: kf0 (LDS A) — prefetch kf5 hb */                                      \
    hb_c = HB(5, RD);                                                            \
    M4L(hb_n)                                                                    \
    /* p2: kf5 — prefetch kf1 operands */                                        \
    hb_n = HB(1, RD);                                                            \
    a0 = AF(1, 0); a1 = AF(1, 1); a2 = AF(1, 2); a3 = AF(1, 3);                  \
    M4R(1, hb_c)                                                                 \
    /* p3: kf1 — prefetch kf6 hb */                                              \
    hb_c = HB(6, RD);                                                            \
    M4L(hb_n)                                                                    \
    /* p4: kf6 — prefetch kf2 operands */                                        \
    hb_n = HB(2, RD);                                                            \
    a0 = AF(2, 0); a1 = AF(2, 1); a2 = AF(2, 2); a3 = AF(2, 3);                  \
    M4R(2, hb_c)                                                                 \
    /* p5: kf2 — prefetch kf7 hb */                                              \
    hb_c = HB(7, RD);                                                            \
    M4L(hb_n)                                                                    \
    /* p6: kf7 — prefetch kf3 operands */                                        \
    hb_n = HB(3, RD);                                                            \
    a0 = AF(3, 0); a1 = AF(3, 1); a2 = AF(3, 2); a3 = AF(3, 3);                  \
    M4R(3, hb_c)                                                                 \
    /* p7: kf3 — prefetch kf8 hb */                                              \
    hb_c = HB(8, RD);                                                            \
    M4L(hb_n)                                                                    \
    /* xp(s) loads: A-pipeline regs dead now; ~8 phases of cover to epilogue */  \
    const float* xrs = xrow0 + (size_t)s * (64 * HID);                           \
    f32x4 xt0 = *reinterpret_cast<const f32x4*>(xrs);                            \
    f32x4 xt1 = *reinterpret_cast<const f32x4*>(xrs + 16);                       \
    f32x4 xt2 = *reinterpret_cast<const f32x4*>(xrs + 32);                       \
    f32x4 xt3 = *reinterpret_cast<const f32x4*>(xrs + 48);                       \
    /* p8..p15: kf8..15 (reg A), alternating hb slots */                         \
    hb_n = HB(9, RD);  M4R(4, hb_c)                                              \
    hb_c = HB(10, RD); M4R(5, hb_n)                                              \
    hb_n = HB(11, RD); M4R(6, hb_c)                                              \
    hb_c = HB(12, RD); M4R(7, hb_n)                                              \
    hb_n = HB(13, RD); M4R(8, hb_c)                                              \
    hb_c = HB(14, RD); M4R(9, hb_n)                                              \
    hb_n = HB(15, RD); M4R(10, hb_c)                                             \
    M4R(11, hb_n)                                                                \
    /* epilogue: acc += xp, tanh, store f32 out, write bf16 h to WR buf */       \
    float* orow = xrow0 + (size_t)s * (64 * HID);                                \
    f32x4 hv0, hv1, hv2, hv3;                                                    \
    _Pragma("unroll")                                                            \
    for (int r = 0; r < 4; ++r) {                                                \
      hv0[r] = 1.0f - 2.0f * __builtin_amdgcn_rcpf(1.0f + __expf(2.0f * (acc0[r] + xt0[r]))); \
      hv1[r] = 1.0f - 2.0f * __builtin_amdgcn_rcpf(1.0f + __expf(2.0f * (acc1[r] + xt1[r]))); \
      hv2[r] = 1.0f - 2.0f * __builtin_amdgcn_rcpf(1.0f + __expf(2.0f * (acc2[r] + xt2[r]))); \
      hv3[r] = 1.0f - 2.0f * __builtin_amdgcn_rcpf(1.0f + __expf(2.0f * (acc3[r] + xt3[r]))); \
    }                                                                            \
    *reinterpret_cast<f32x4*>(orow)      = hv0;                                  \
    *reinterpret_cast<f32x4*>(orow + 16) = hv1;                                  \
    *reinterpret_cast<f32x4*>(orow + 32) = hv2;                                  \
    *reinterpret_cast<f32x4*>(orow + 48) = hv3;                                  \
    uint2 hp;                                                                    \
    hp.x = (unsigned)f2bf(hv0[0]) | ((unsigned)f2bf(hv0[1]) << 16);              \
    hp.y = (unsigned)f2bf(hv0[2]) | ((unsigned)f2bf(hv0[3]) << 16);              \
    *reinterpret_cast<uint2*>(smem + 131072 + (WR) + ((wpre + 0 * 32) ^ hswz)) = hp; \
    hp.x = (unsigned)f2bf(hv1[0]) | ((unsigned)f2bf(hv1[1]) << 16);              \
    hp.y = (unsigned)f2bf(hv1[2]) | ((unsigned)f2bf(hv1[3]) << 16);              \
    *reinterpret_cast<uint2*>(smem + 131072 + (WR) + ((wpre + 1 * 32) ^ hswz)) = hp; \
    hp.x = (unsigned)f2bf(hv2[0]) | ((unsigned)f2bf(hv2[1]) << 16);              \
    hp.y = (unsigned)f2bf(hv2[2]) | ((unsigned)f2bf(hv2[3]) << 16);              \
    *reinterpret_cast<uint2*>(smem + 131072 + (WR) + ((wpre + 2 * 32) ^ hswz)) = hp; \
    hp.x = (unsigned)f2bf(hv3[0]) | ((unsigned)f2bf(hv3[1]) << 16);              \
    hp.y = (unsigned)f2bf(hv3[2]) | ((unsigned)f2bf(hv3[3]) << 16);              \
    *reinterpret_cast<uint2*>(smem + 131072 + (WR) + ((wpre + 3 * 32) ^ hswz)) = hp; \
    /* fused fence+barrier: one memory-clobber point; rest of step schedulable */\
    asm volatile("s_waitcnt lgkmcnt(0)\n\ts_barrier" ::: "memory");              \
  }

  #pragma unroll 1
  for (int s2 = 0; s2 < SEQ; s2 += 2) {
    SCAN_STEP(s2,     0,     16384)
    SCAN_STEP(s2 + 1, 16384, 0)
  }
#undef SCAN_STEP
#undef HB
#undef AF
#undef M4R
#undef M4L
}

extern "C" void kernel_launch(void* const* d_in, const int* in_sizes, int n_in,
                              void* d_out, int out_size, void* d_ws, size_t ws_size,
                              hipStream_t stream) {
  (void)in_sizes; (void)n_in; (void)out_size;
  const float* X   = (const float*)d_in[0];
  const float* Wih = (const float*)d_in[1];
  const float* Whh = (const float*)d_in[2];
  const float* bih = (const float*)d_in[3];
  const float* bhh = (const float*)d_in[4];
  float* out = (float*)d_out;

  unsigned short* wihf = (unsigned short*)d_ws;              // 512 KB
  unsigned short* whhf = wihf + 262144;                      // 512 KB
  float* bsum = (float*)(whhf + 262144);                     // 2 KB
  if (ws_size < (size_t)(2 * 524288 + 2048)) return;

  prep_wfrag<<<1024, 256, 0, stream>>>(Wih, wihf);
  prep_wfrag<<<1024, 256, 0, stream>>>(Whh, whhf);
  prep_bsum<<<1, 512, 0, stream>>>(bih, bhh, bsum);

  rnn_xproj<<<2048, 512, 0, stream>>>(X, (const uint4*)wihf, bsum, out);

  hipFuncSetAttribute(reinterpret_cast<const void*>(rnn_scan),
                      hipFuncAttributeMaxDynamicSharedMemorySize, 163840);
  rnn_scan<<<4, 512, 163840, stream>>>((const uint4*)whhf, out);
}